// Round 8
// baseline (138.826 us; speedup 1.0000x reference)
//
#include <hip/hip_runtime.h>
#include <stdint.h>

#define EPS_F 1e-7f

typedef float f32x4 __attribute__((ext_vector_type(4)));
typedef int   v8i   __attribute__((ext_vector_type(8)));

// 8 consecutive VGPRs: two b128 loads land directly in the MFMA operand tuple.
union A32 { uint4 u4[2]; v8i v; };

__device__ __forceinline__ unsigned cvt4(float a, float b, float c, float d) {
  int v = __builtin_amdgcn_cvt_pk_fp8_f32(a, b, 0, false);   // bytes 0,1
  return (unsigned)__builtin_amdgcn_cvt_pk_fp8_f32(c, d, v, true);  // bytes 2,3
}

// MX-scaled fp8 MFMA, K=128, scales = 1.0 (e8m0 127 in every byte -> opsel-proof).
// cbsz=0 (A fmt fp8 e4m3), blgp=0 (B fmt fp8 e4m3).
#define MFMA128(A, B, C) __builtin_amdgcn_mfma_scale_f32_16x16x128_f8f6f4( \
    (A), (B), (C), 0, 0, 0, 0x7F7F7F7F, 0, 0x7F7F7F7F)

// ---------------------------------------------------------------------------
// Shared software k-order for BOTH operand images (permutation-invariance over
// K + symmetric A/B fragment layouts make any HW intra-instruction k-mapping
// cancel, as long as A and B use the same (lane,byte)->k function):
//   fragment lane = kg*16 + (row|col)&15,  kg = lane>>4
//   nominal k  = kb*128 + kg*32 + j,  j in [0,32)
//   j in [0,16)  -> LO plane (one b128),  j in [16,32) -> HI plane (one b128)
// B image: run index ri = (g*4 + kb)*64 + lane, planes of 512 KB each.
// R5/R6/R7 verified end-to-end (absmax 0).
// ---------------------------------------------------------------------------

// ---------------------------------------------------------------------------
// prep: protos fp32 (2048x512) -> fp8 e4m3 B image in the layout above.
// (unchanged from R5 — verified)
// ---------------------------------------------------------------------------
__global__ __launch_bounds__(256) void prep_kernel(
    const float* __restrict__ protos, uint8_t* __restrict__ wsB,
    float* __restrict__ y2a, float* __restrict__ rya,
    float* __restrict__ out) {
  const int lane = threadIdx.x & 63;
  const int w    = threadIdx.x >> 6;
  const int c    = blockIdx.x * 4 + w;
  const int g    = c >> 4, cl = c & 15;
  const float4* p = (const float4*)(protos + (size_t)c * 512 + lane * 8);
  float4 f0 = p[0], f1 = p[1];
  float s = f0.x*f0.x + f0.y*f0.y + f0.z*f0.z + f0.w*f0.w
          + f1.x*f1.x + f1.y*f1.y + f1.z*f1.z + f1.w*f1.w;
#pragma unroll
  for (int off = 32; off > 0; off >>= 1) s += __shfl_xor(s, off, 64);
  if (lane == 0) { y2a[c] = s; rya[c] = 1.f / (1.f - s); }
  unsigned ux = cvt4(f0.x, f0.y, f0.z, f0.w);   // k [8l, 8l+4)
  unsigned uy = cvt4(f1.x, f1.y, f1.z, f1.w);   // k [8l+4, 8l+8)
  const int kb = lane >> 4, kg = (lane >> 2) & 3, bo = lane & 3;
  size_t ri  = (size_t)(g * 4 + kb) * 64 + kg * 16 + cl;
  size_t off = ri * 16 + (size_t)(bo & 1) * 8 + (size_t)(bo >> 1) * (512u * 1024u);
  *(uint2*)(wsB + off) = make_uint2(ux, uy);
  if (blockIdx.x == 0 && threadIdx.x == 0) out[0] = 0.f;
}

// ---------------------------------------------------------------------------
// gemm_min v8: A-IN-REGISTERS.  512 blocks x 256 thr (4 waves),
// launch_bounds(256,1) -> VGPR cap 256 (R5-measured: allocator lands under
// cap without spill).
// ROUND-7 DIAGNOSIS (model now closes): per-SIMD MFMA cost is 34.5 cyc/inst
// (4661 TF MX ceiling / 256 CU / 4 SIMD), so per-SIMD MFMA demand = 14.7 us;
// measured MfmaUtil*dur = 13.4 us in EVERY round while no pipe exceeds ~35%
// busy -> the limiter is per-wave serialization (ds burst -> lgkm wait ->
// vmcnt wait -> MFMA burst) with all waves in the same phase; halving LDS
// traffic (R6->R7) changed nothing.  Fix: remove the in-loop LDS dependency
// entirely.  A wave's 64x512 fp8 A-tile = 128 B/lane = 128 VGPRs -> hold ALL
// of A in registers; main loop = pure {B global load -> MFMA}:
//   - per kb-step: 4 global b128 (B, depth-2 pipeline) + 8 MFMA(K=128);
//     zero ds_read, zero barriers.  8 MFMAs = ~276 cyc of matrix-pipe time
//     >= L2 latency (~250) -> depth-2 prefetch covers latency within ONE
//     wave; 2 waves/SIMD (VGPR-limited) add margin.
//   - staging: R7 code verbatim (one barrier), then each wave copies the
//     32 KB A tile LDS->regs once (32 ds_read_b128).
//   - wave w: cols [w*512,+512), 16 s-iters x 32 cols (frags g0=w*32+2s,
//     g1=g0+1).  B-traffic per CU unchanged (2 MB, L2-resident).
//   - register ledger: a 128 + Bp 32 + acc 32 + x2r 16 + tmin 16 + temps
//     ~15 = ~240 < 256.  Watch: WRITE_SIZE in MB => spilled => abort line.
//   - epilogue per 32-col strip: tmin = min(tmin, max(x2+y2-2dot,0)*ry);
//     1/(1-x2) folded once per row at the end (monotone, rx>0).
// ---------------------------------------------------------------------------
__global__ __launch_bounds__(256, 1) void gemm_min_kernel(
    const float* __restrict__ z, const uint8_t* __restrict__ wsB,
    const float* __restrict__ y2a, const float* __restrict__ rya,
    const float* __restrict__ marg, float* __restrict__ out) {
  __shared__ uint4 AsLo[1024];   // (kb*4 + rf)*64 + lane   (16 KB)
  __shared__ uint4 AsHi[1024];   // same index, k-bytes 16..31 (16 KB)
  __shared__ float x2s[64];
  __shared__ float rxs[64];
  __shared__ float minbuf[64][4];

  const int tid  = threadIdx.x;
  const int lane = tid & 63;
  const int w    = tid >> 6;          // wave 0..3
  const int q    = lane >> 4;         // kg / acc row-group
  const int l15  = lane & 15;
  const size_t rowbase = (size_t)blockIdx.x * 64;

  const uint4* BLo = (const uint4*)wsB;
  const uint4* BHi = BLo + 32768;     // +512 KB

  // ---- B warm-up (steps i=0,1) first: overlaps the staging barrier ----
  // wave w owns cols [w*512,+512): frag pair g0 = w*32 + 2s, g1 = g0+1.
  // linear step i = s*4 + kb; chunk ri0 = (w*128 + 8s + kb)*64 + lane,
  // ri1 = ri0 + 256; slot = i&1 (= kb&1, since s*4 is even).
  A32 Bp0[2], Bp1[2];
#pragma unroll
  for (int i = 0; i < 2; ++i) {
    size_t r0 = (size_t)(w * 128 + i) * 64 + lane;
    Bp0[i].u4[0] = BLo[r0];       Bp0[i].u4[1] = BHi[r0];
    Bp1[i].u4[0] = BLo[r0 + 256]; Bp1[i].u4[1] = BHi[r0 + 256];
  }

  // ---- A staging + fused x2: wave w(=rf) owns rows w*16 + l15 (R5 code) ----
  // lane (q,l15): k quarter [q*128, +128) of its row, 4 sub-runs of 32.
  {
    const float* rp0 = z + (rowbase + w * 16 + l15) * 512 + q * 128;
    float s = 0.f;
#pragma unroll
    for (int t = 0; t < 4; ++t) {
      const float4* rp = (const float4*)(rp0 + t * 32);
      float4 v0 = rp[0], v1 = rp[1], v2 = rp[2], v3 = rp[3];
      float4 v4 = rp[4], v5 = rp[5], v6 = rp[6], v7 = rp[7];
      s += v0.x*v0.x + v0.y*v0.y + v0.z*v0.z + v0.w*v0.w
         + v1.x*v1.x + v1.y*v1.y + v1.z*v1.z + v1.w*v1.w
         + v2.x*v2.x + v2.y*v2.y + v2.z*v2.z + v2.w*v2.w
         + v3.x*v3.x + v3.y*v3.y + v3.z*v3.z + v3.w*v3.w
         + v4.x*v4.x + v4.y*v4.y + v4.z*v4.z + v4.w*v4.w
         + v5.x*v5.x + v5.y*v5.y + v5.z*v5.z + v5.w*v5.w
         + v6.x*v6.x + v6.y*v6.y + v6.z*v6.z + v6.w*v6.w
         + v7.x*v7.x + v7.y*v7.y + v7.z*v7.z + v7.w*v7.w;
      uint4 lo, hi;
      lo.x = cvt4(v0.x, v0.y, v0.z, v0.w);
      lo.y = cvt4(v1.x, v1.y, v1.z, v1.w);
      lo.z = cvt4(v2.x, v2.y, v2.z, v2.w);
      lo.w = cvt4(v3.x, v3.y, v3.z, v3.w);
      hi.x = cvt4(v4.x, v4.y, v4.z, v4.w);
      hi.y = cvt4(v5.x, v5.y, v5.z, v5.w);
      hi.z = cvt4(v6.x, v6.y, v6.z, v6.w);
      hi.w = cvt4(v7.x, v7.y, v7.z, v7.w);
      int ri = (q * 4 + w) * 64 + t * 16 + l15;   // chunk (kb=q, rf=w), kg=t
      AsLo[ri] = lo; AsHi[ri] = hi;
    }
    s += __shfl_xor(s, 16, 64);
    s += __shfl_xor(s, 32, 64);      // sum over the 4 q-lanes of this row
    if (lane < 16) { x2s[w * 16 + lane] = s; rxs[w * 16 + lane] = 1.f / (1.f - s); }
  }
  __syncthreads();  // the ONLY barrier before the final reduction

  // ---- A tile LDS -> registers, once: 32 ds_read_b128 per wave ----
  A32 a[4][4];   // [rf][kb], 128 VGPRs
#pragma unroll
  for (int rf = 0; rf < 4; ++rf) {
#pragma unroll
    for (int kb = 0; kb < 4; ++kb) {
      int ri = (kb * 4 + rf) * 64 + lane;
      a[rf][kb].u4[0] = AsLo[ri];
      a[rf][kb].u4[1] = AsHi[ri];
    }
  }

  // x2 resident per lane: rows rf*16 + q*4 + r
  float x2r[4][4];
#pragma unroll
  for (int rf = 0; rf < 4; ++rf) {
    float4 x4 = *(const float4*)&x2s[rf * 16 + q * 4];
    x2r[rf][0] = x4.x; x2r[rf][1] = x4.y; x2r[rf][2] = x4.z; x2r[rf][3] = x4.w;
  }

  float tmin[4][4];
#pragma unroll
  for (int rf = 0; rf < 4; ++rf)
#pragma unroll
    for (int r = 0; r < 4; ++r) tmin[rf][r] = 3.4e38f;

  const float* y2p = y2a + w * 512 + l15;
  const float* ryp = rya + w * 512 + l15;

#pragma clang loop unroll(disable)
  for (int s = 0; s < 16; ++s) {
    f32x4 acc[4][2];
#pragma unroll
    for (int rf = 0; rf < 4; ++rf) {
      f32x4 z4 = {0.f, 0.f, 0.f, 0.f};
      acc[rf][0] = z4; acc[rf][1] = z4;
    }
    float y2v0 = y2p[s * 32],      ryv0 = ryp[s * 32];
    float y2v1 = y2p[s * 32 + 16], ryv1 = ryp[s * 32 + 16];

#pragma unroll
    for (int kb = 0; kb < 4; ++kb) {
      v8i bv0 = Bp0[kb & 1].v;
      v8i bv1 = Bp1[kb & 1].v;
      {  // prefetch step i+2 into the just-consumed slot (pad absorbs tail)
        int ip = s * 4 + kb + 2;
        size_t r0 = (size_t)(w * 128 + (ip >> 2) * 8 + (ip & 3)) * 64 + lane;
        Bp0[kb & 1].u4[0] = BLo[r0];       Bp0[kb & 1].u4[1] = BHi[r0];
        Bp1[kb & 1].u4[0] = BLo[r0 + 256]; Bp1[kb & 1].u4[1] = BHi[r0 + 256];
      }
#pragma unroll
      for (int rf = 0; rf < 4; ++rf) {
        acc[rf][0] = MFMA128(a[rf][kb].v, bv0, acc[rf][0]);
        acc[rf][1] = MFMA128(a[rf][kb].v, bv1, acc[rf][1]);
      }
    }

    // epilogue: cols c0 = w*512 + s*32 + l15, c1 = c0 + 16
#pragma unroll
    for (int rf = 0; rf < 4; ++rf) {
#pragma unroll
      for (int r = 0; r < 4; ++r) {
        float xv = x2r[rf][r];
        float u0 = fmaxf(fmaf(-2.f, acc[rf][0][r], xv + y2v0), 0.f) * ryv0;
        float u1 = fmaxf(fmaf(-2.f, acc[rf][1][r], xv + y2v1), 0.f) * ryv1;
        tmin[rf][r] = fminf(tmin[rf][r], fminf(u0, u1));
      }
    }
  }

  // ---- min across the 16 lanes (l15) sharing each row ----
#pragma unroll
  for (int rf = 0; rf < 4; ++rf) {
#pragma unroll
    for (int r = 0; r < 4; ++r) {
      float v = tmin[rf][r];
      v = fminf(v, __shfl_xor(v, 1, 64));
      v = fminf(v, __shfl_xor(v, 2, 64));
      v = fminf(v, __shfl_xor(v, 4, 64));
      v = fminf(v, __shfl_xor(v, 8, 64));
      if (l15 == 0) minbuf[rf * 16 + q * 4 + r][w] = v;
    }
  }
  __syncthreads();

  if (w == 0) {  // lane = row 0..63
    float m = fminf(fminf(minbuf[lane][0], minbuf[lane][1]),
                    fminf(minbuf[lane][2], minbuf[lane][3]));
    float t = m * rxs[lane];                 // fold 1/(1-x2) once per row
    float arg = fmaxf(fmaf(2.f, t, 1.f), 1.f + EPS_F);
    float contrib = fmaxf(marg[0] - acoshf(arg), 0.f);
#pragma unroll
    for (int off = 32; off > 0; off >>= 1) contrib += __shfl_xor(contrib, off, 64);
    if (lane == 0) atomicAdd(out, contrib * (1.0f / 32768.f));
  }
}

// ---------------------------------------------------------------------------
extern "C" void kernel_launch(void* const* d_in, const int* in_sizes, int n_in,
                              void* d_out, int out_size, void* d_ws, size_t ws_size,
                              hipStream_t stream) {
  const float* z      = (const float*)d_in[0];  // 32768 x 512 fp32
  const float* protos = (const float*)d_in[1];  // 2048 x 512 fp32
  const float* marg   = (const float*)d_in[2];  // scalar
  float* out = (float*)d_out;
  uint8_t* wsB = (uint8_t*)d_ws;                // 1 MB image (lo/hi 512 KB planes)
  // 192 KB pad absorbs the harmless B-pipeline tail over-reads (<= 64 KB).
  float* y2a = (float*)((char*)d_ws + (1 << 20) + 192 * 1024);   // 8 KB
  float* rya = y2a + 2048;                                       // 8 KB

  prep_kernel<<<512, 256, 0, stream>>>(protos, wsB, y2a, rya, out);
  gemm_min_kernel<<<512, 256, 0, stream>>>(z, wsB, y2a, rya, marg, out);
}

// Round 9
// 135.266 us; speedup vs baseline: 1.0263x; 1.0263x over previous
//
#include <hip/hip_runtime.h>
#include <stdint.h>

#define EPS_F 1e-7f

typedef float f32x4 __attribute__((ext_vector_type(4)));
typedef int   v8i   __attribute__((ext_vector_type(8)));

// 8 consecutive VGPRs: two b128 loads land directly in the MFMA operand tuple.
union A32 { uint4 u4[2]; v8i v; };

__device__ __forceinline__ unsigned cvt4(float a, float b, float c, float d) {
  int v = __builtin_amdgcn_cvt_pk_fp8_f32(a, b, 0, false);   // bytes 0,1
  return (unsigned)__builtin_amdgcn_cvt_pk_fp8_f32(c, d, v, true);  // bytes 2,3
}

// MX-scaled fp8 MFMA, K=128, scales = 1.0 (e8m0 127 in every byte -> opsel-proof).
#define MFMA128(A, B, C) __builtin_amdgcn_mfma_scale_f32_16x16x128_f8f6f4( \
    (A), (B), (C), 0, 0, 0, 0x7F7F7F7F, 0, 0x7F7F7F7F)

// ---------------------------------------------------------------------------
// Shared software k-order for BOTH operand images (R5-R8 verified, absmax 0):
//   fragment lane = kg*16 + (row|col)&15,  kg = lane>>4
//   nominal k  = kb*128 + kg*32 + j,  j in [0,32)
//   j in [0,16)  -> LO plane (granule idx ri),  j in [16,32) -> HI (ri+1024)
// B image: run index ri = (g*4 + kb)*64 + lane, planes of 512 KB each.
// ---------------------------------------------------------------------------

// ---------------------------------------------------------------------------
// prep: protos fp32 (2048x512) -> fp8 e4m3 B image (unchanged from R5).
// ---------------------------------------------------------------------------
__global__ __launch_bounds__(256) void prep_kernel(
    const float* __restrict__ protos, uint8_t* __restrict__ wsB,
    float* __restrict__ y2a, float* __restrict__ rya,
    float* __restrict__ out) {
  const int lane = threadIdx.x & 63;
  const int w    = threadIdx.x >> 6;
  const int c    = blockIdx.x * 4 + w;
  const int g    = c >> 4, cl = c & 15;
  const float4* p = (const float4*)(protos + (size_t)c * 512 + lane * 8);
  float4 f0 = p[0], f1 = p[1];
  float s = f0.x*f0.x + f0.y*f0.y + f0.z*f0.z + f0.w*f0.w
          + f1.x*f1.x + f1.y*f1.y + f1.z*f1.z + f1.w*f1.w;
#pragma unroll
  for (int off = 32; off > 0; off >>= 1) s += __shfl_xor(s, off, 64);
  if (lane == 0) { y2a[c] = s; rya[c] = 1.f / (1.f - s); }
  unsigned ux = cvt4(f0.x, f0.y, f0.z, f0.w);   // k [8l, 8l+4)
  unsigned uy = cvt4(f1.x, f1.y, f1.z, f1.w);   // k [8l+4, 8l+8)
  const int kb = lane >> 4, kg = (lane >> 2) & 3, bo = lane & 3;
  size_t ri  = (size_t)(g * 4 + kb) * 64 + kg * 16 + cl;
  size_t off = ri * 16 + (size_t)(bo & 1) * 8 + (size_t)(bo >> 1) * (512u * 1024u);
  *(uint2*)(wsB + off) = make_uint2(ux, uy);
  if (blockIdx.x == 0 && threadIdx.x == 0) out[0] = 0.f;
}

// ---------------------------------------------------------------------------
// gemm_min v9: COALESCED STAGING.  512 blocks x 512 thr (8 waves),
// launch_bounds(512,1) -> VGPR cap 128 (R6/R7: no spill, WRITE 16 B).
// ROUND-8 DIAGNOSIS: four main-loop variants (R5-R8) all land at 61-70 us
// with MFMA busy pinned at 13-14 us -> the loop was never the limiter.  The
// constant across rounds is the STRIDED staging read: lane q*16+l15 reads
// 16 B at 2 KB row stride -> 64 cache lines PER INSTRUCTION, ~16K line
// transactions per CU serialized through TA/L1 at block start = the ~30 us
// of exposed latency.  Fix: coalesced 1 KB wave-bursts (16 lines/instr,
// lines fully used) + in-wave 4-lane 4x4 transpose (shfl_xor) to assemble
// fragment granules; ds_write_b128 to THE SAME addresses R7's main loop
// reads — read path untouched.  All 8 waves stage 8 rows each.
//   - main loop (R7 verbatim): per kb-step 8 ds_read_b128 + 8 MFMA(K=128)
//     + 4 global b128 (B depth-2 pipeline); one barrier total.
//   - x2 stays fp32-exact: per-row wave reductions of per-lane partials.
// ---------------------------------------------------------------------------
__global__ __launch_bounds__(512, 1) void gemm_min_kernel(
    const float* __restrict__ z, const uint8_t* __restrict__ wsB,
    const float* __restrict__ y2a, const float* __restrict__ rya,
    const float* __restrict__ marg, float* __restrict__ out) {
  __shared__ uint4 As2[2048];    // [pl*1024 + (kb*4+rf)*64 + kg*16 + r15]  32 KB
  __shared__ float x2s[64];
  __shared__ float rxs[64];
  __shared__ float minbuf[64][8];

  const int tid  = threadIdx.x;
  const int lane = tid & 63;
  const int w    = tid >> 6;          // wave 0..7
  const int q    = lane >> 4;         // kg / acc row-group
  const int l15  = lane & 15;
  const size_t rowbase = (size_t)blockIdx.x * 64;

  const uint4* BLo = (const uint4*)wsB;
  const uint4* BHi = BLo + 32768;     // +512 KB

  // ---- B warm-up (steps i=0,1) first: overlaps staging latency ----
  // wave w owns cols [w*256,+256): frag pair g0 = w*16 + 2s, g1 = g0+1.
  // linear step i = s*4 + kb; slot = i&1 (= kb&1).
  A32 Bp0[2], Bp1[2];
#pragma unroll
  for (int i = 0; i < 2; ++i) {
    size_t r0 = (size_t)(w * 64 + i) * 64 + lane;
    Bp0[i].u4[0] = BLo[r0];       Bp0[i].u4[1] = BHi[r0];
    Bp1[i].u4[0] = BLo[r0 + 256]; Bp1[i].u4[1] = BHi[r0 + 256];
  }

  // ---- A staging, coalesced: wave w owns rows [w*8, w*8+8) ----
  // super-step ss: 4 loads, each a contiguous 1 KB wave-burst:
  //   jj=0,1 -> row 2ss,   k-half jj&1;  jj=2,3 -> row 2ss+1.
  // lane holds 4 floats -> cvt -> u32; 4x4 transpose among lanes 4m+c
  // (value index <-> lane index) so lane 4m+c holds one full granule:
  //   row 2ss+(c>>1), K = 256*(c&1) + 16*m, bytes [K, K+16) ascending.
  {
    const int c4 = lane & 3;
    const int m  = lane >> 2;           // 0..15
    const float* zb = z + (rowbase + w * 8) * 512 + lane * 4;
    float p0 = 0.f, p1 = 0.f, p2 = 0.f, p3 = 0.f,
          p4 = 0.f, p5 = 0.f, p6 = 0.f, p7 = 0.f;
#pragma unroll
    for (int ss = 0; ss < 4; ++ss) {
      float4 f0 = *(const float4*)(zb + (2 * ss + 0) * 512);
      float4 f1 = *(const float4*)(zb + (2 * ss + 0) * 512 + 256);
      float4 f2 = *(const float4*)(zb + (2 * ss + 1) * 512);
      float4 f3 = *(const float4*)(zb + (2 * ss + 1) * 512 + 256);
      float sa = f0.x*f0.x + f0.y*f0.y + f0.z*f0.z + f0.w*f0.w
               + f1.x*f1.x + f1.y*f1.y + f1.z*f1.z + f1.w*f1.w;
      float sb = f2.x*f2.x + f2.y*f2.y + f2.z*f2.z + f2.w*f2.w
               + f3.x*f3.x + f3.y*f3.y + f3.z*f3.z + f3.w*f3.w;
      if (ss == 0) { p0 += sa; p1 += sb; }
      if (ss == 1) { p2 += sa; p3 += sb; }
      if (ss == 2) { p4 += sa; p5 += sb; }
      if (ss == 3) { p6 += sa; p7 += sb; }
      unsigned v0 = cvt4(f0.x, f0.y, f0.z, f0.w);
      unsigned v1 = cvt4(f1.x, f1.y, f1.z, f1.w);
      unsigned v2 = cvt4(f2.x, f2.y, f2.z, f2.w);
      unsigned v3 = cvt4(f3.x, f3.y, f3.z, f3.w);
      unsigned t;
      // stage A (xor 1): swap index-bit0 <-> lane-bit0
      t = (unsigned)__shfl_xor((int)((c4 & 1) ? v0 : v1), 1, 64);
      if (c4 & 1) v0 = t; else v1 = t;
      t = (unsigned)__shfl_xor((int)((c4 & 1) ? v2 : v3), 1, 64);
      if (c4 & 1) v2 = t; else v3 = t;
      // stage B (xor 2): swap index-bit1 <-> lane-bit1
      t = (unsigned)__shfl_xor((int)((c4 & 2) ? v0 : v2), 2, 64);
      if (c4 & 2) v0 = t; else v2 = t;
      t = (unsigned)__shfl_xor((int)((c4 & 2) ? v1 : v3), 2, 64);
      if (c4 & 2) v1 = t; else v3 = t;
      // lane now holds granule (v0..v3 = source lanes 4m+0..3, k ascending)
      int K   = ((c4 & 1) << 8) + (m << 4);
      int kb  = K >> 7;
      int kg  = (K >> 5) & 3;
      int pl  = (K >> 4) & 1;
      int r15 = ((w & 1) << 3) + 2 * ss + (c4 >> 1);
      int rf  = w >> 1;
      int ri  = pl * 1024 + (kb * 4 + rf) * 64 + kg * 16 + r15;
      As2[ri] = make_uint4(v0, v1, v2, v3);
    }
    // exact fp32 row sums: one wave-reduction per row
    float pr[8] = {p0, p1, p2, p3, p4, p5, p6, p7};
#pragma unroll
    for (int i = 0; i < 8; ++i) {
      float v = pr[i];
#pragma unroll
      for (int off = 32; off > 0; off >>= 1) v += __shfl_xor(v, off, 64);
      if (lane == 0) { x2s[w * 8 + i] = v; rxs[w * 8 + i] = 1.f / (1.f - v); }
    }
  }
  __syncthreads();  // the ONLY barrier before the final reduction

  // x2 resident per lane: rows rf*16 + q*4 + r
  float x2r[4][4];
#pragma unroll
  for (int rf = 0; rf < 4; ++rf) {
    float4 x4 = *(const float4*)&x2s[rf * 16 + q * 4];
    x2r[rf][0] = x4.x; x2r[rf][1] = x4.y; x2r[rf][2] = x4.z; x2r[rf][3] = x4.w;
  }

  float tmin[4][4];
#pragma unroll
  for (int rf = 0; rf < 4; ++rf)
#pragma unroll
    for (int r = 0; r < 4; ++r) tmin[rf][r] = 3.4e38f;

  const float* y2p = y2a + w * 256 + l15;
  const float* ryp = rya + w * 256 + l15;

#pragma clang loop unroll(disable)
  for (int s = 0; s < 8; ++s) {
    f32x4 acc[4][2];
#pragma unroll
    for (int rf = 0; rf < 4; ++rf) {
      f32x4 z4 = {0.f, 0.f, 0.f, 0.f};
      acc[rf][0] = z4; acc[rf][1] = z4;
    }
    float y2v0 = y2p[s * 32],      ryv0 = ryp[s * 32];
    float y2v1 = y2p[s * 32 + 16], ryv1 = ryp[s * 32 + 16];

#pragma unroll
    for (int kb = 0; kb < 4; ++kb) {
      // consume slot kb&1 (loaded 2 steps ago)
#pragma unroll
      for (int rf = 0; rf < 4; ++rf) {
        A32 a;
        int ri = (kb * 4 + rf) * 64 + lane;
        a.u4[0] = As2[ri];
        a.u4[1] = As2[1024 + ri];
        acc[rf][0] = MFMA128(a.v, Bp0[kb & 1].v, acc[rf][0]);
        acc[rf][1] = MFMA128(a.v, Bp1[kb & 1].v, acc[rf][1]);
      }
      {  // prefetch step i+2 into the just-consumed slot (pad absorbs tail)
        int ip = s * 4 + kb + 2;
        size_t r0 = (size_t)(w * 64 + (ip >> 2) * 8 + (ip & 3)) * 64 + lane;
        Bp0[kb & 1].u4[0] = BLo[r0];       Bp0[kb & 1].u4[1] = BHi[r0];
        Bp1[kb & 1].u4[0] = BLo[r0 + 256]; Bp1[kb & 1].u4[1] = BHi[r0 + 256];
      }
    }

    // epilogue: cols c0 = w*256 + s*32 + l15, c1 = c0 + 16
#pragma unroll
    for (int rf = 0; rf < 4; ++rf) {
#pragma unroll
      for (int r = 0; r < 4; ++r) {
        float xv = x2r[rf][r];
        float u0 = fmaxf(fmaf(-2.f, acc[rf][0][r], xv + y2v0), 0.f) * ryv0;
        float u1 = fmaxf(fmaf(-2.f, acc[rf][1][r], xv + y2v1), 0.f) * ryv1;
        tmin[rf][r] = fminf(tmin[rf][r], fminf(u0, u1));
      }
    }
  }

  // ---- min across the 16 lanes (l15) sharing each row ----
#pragma unroll
  for (int rf = 0; rf < 4; ++rf) {
#pragma unroll
    for (int r = 0; r < 4; ++r) {
      float v = tmin[rf][r];
      v = fminf(v, __shfl_xor(v, 1, 64));
      v = fminf(v, __shfl_xor(v, 2, 64));
      v = fminf(v, __shfl_xor(v, 4, 64));
      v = fminf(v, __shfl_xor(v, 8, 64));
      if (l15 == 0) minbuf[rf * 16 + q * 4 + r][w] = v;
    }
  }
  __syncthreads();

  if (w == 0) {  // lane = row 0..63
    float m = minbuf[lane][0];
#pragma unroll
    for (int i = 1; i < 8; ++i) m = fminf(m, minbuf[lane][i]);
    float t = m * rxs[lane];                 // fold 1/(1-x2) once per row
    float arg = fmaxf(fmaf(2.f, t, 1.f), 1.f + EPS_F);
    float contrib = fmaxf(marg[0] - acoshf(arg), 0.f);
#pragma unroll
    for (int off = 32; off > 0; off >>= 1) contrib += __shfl_xor(contrib, off, 64);
    if (lane == 0) atomicAdd(out, contrib * (1.0f / 32768.f));
  }
}

// ---------------------------------------------------------------------------
extern "C" void kernel_launch(void* const* d_in, const int* in_sizes, int n_in,
                              void* d_out, int out_size, void* d_ws, size_t ws_size,
                              hipStream_t stream) {
  const float* z      = (const float*)d_in[0];  // 32768 x 512 fp32
  const float* protos = (const float*)d_in[1];  // 2048 x 512 fp32
  const float* marg   = (const float*)d_in[2];  // scalar
  float* out = (float*)d_out;
  uint8_t* wsB = (uint8_t*)d_ws;                // 1 MB image (lo/hi 512 KB planes)
  // 192 KB pad absorbs the harmless B-pipeline tail over-reads (<= 32 KB).
  float* y2a = (float*)((char*)d_ws + (1 << 20) + 192 * 1024);   // 8 KB
  float* rya = y2a + 2048;                                       // 8 KB

  prep_kernel<<<512, 256, 0, stream>>>(protos, wsB, y2a, rya, out);
  gemm_min_kernel<<<512, 512, 0, stream>>>(z, wsB, y2a, rya, marg, out);
}